// Round 1
// baseline (734.604 us; speedup 1.0000x reference)
//
#include <hip/hip_runtime.h>

typedef unsigned short u16;
typedef unsigned int   u32;
typedef float  floatx4 __attribute__((ext_vector_type(4)));
typedef __bf16 bfx8    __attribute__((ext_vector_type(8)));

#define DEV __device__ __forceinline__

// Problem constants (fixed by reference): B=4, C=256, Ch=128, N=H*W=4096
#define NB 4
#define NC 256
#define NCH 128
#define NSP 4096
#define OUT_OFF 4194304   // floats: 4*256*4096 (out region) before attn region

DEV u16 f2bf(float f) {
  u32 u = __builtin_bit_cast(u32, f);
  u = (u + 0x7fffu + ((u >> 16) & 1u)) >> 16;   // round-to-nearest-even
  return (u16)u;
}

DEV void lds_load16(const u16* g, u16* l) {
  // async global->LDS, 16B per lane; LDS dest must be lane-contiguous per wave
  __builtin_amdgcn_global_load_lds(
      (const __attribute__((address_space(1))) u32*)g,
      (__attribute__((address_space(3))) u32*)l, 16, 0, 0);
}

DEV floatx4 mfma16(bfx8 a, bfx8 b, floatx4 c) {
  return __builtin_amdgcn_mfma_f32_16x16x32_bf16(a, b, c, 0, 0, 0);
}

DEV float rmax16(float v) {
  #pragma unroll
  for (int m = 1; m < 16; m <<= 1) v = fmaxf(v, __shfl_xor(v, m, 64));
  return v;
}
DEV float rsum16(float v) {
  #pragma unroll
  for (int m = 1; m < 16; m <<= 1) v += __shfl_xor(v, m, 64);
  return v;
}

// ---------------- small converters ----------------
__global__ __launch_bounds__(256) void cvt_bf16(const float* __restrict__ s,
                                                u16* __restrict__ d, int n) {
  int i = blockIdx.x * 256 + threadIdx.x;
  if (i < n) d[i] = f2bf(s[i]);
}

// x (B,C,N) fp32 -> xT (B,N,C) bf16, 64x64 LDS tile transpose
__global__ __launch_bounds__(256) void transpose_x(const float* __restrict__ x,
                                                   u16* __restrict__ xT) {
  __shared__ float T[64 * 65];
  const int b = blockIdx.z, c0 = blockIdx.y * 64, n0 = blockIdx.x * 64;
  const int tid = threadIdx.x;
  const int j = tid & 63, r0 = tid >> 6;
  const size_t xbase = ((size_t)b * NC + c0) * NSP + n0;
  #pragma unroll
  for (int s = 0; s < 16; s++) {
    int cl = s * 4 + r0;
    T[cl * 65 + j] = x[xbase + (size_t)cl * NSP + j];
  }
  __syncthreads();
  const size_t tbase = ((size_t)b * NSP + n0) * NC + c0;
  #pragma unroll
  for (int s = 0; s < 16; s++) {
    int nr = s * 4 + r0;
    xT[tbase + (size_t)nr * NC + j] = f2bf(T[j * 65 + nr]);
  }
}

// ---------------- generic B-transposed MFMA GEMM ----------------
// C[b][m][n] = sum_k A[b][m][k] * Bt[b][n][k]  (+bias)(relu)(final: gamma*v+x)
// BIAS: 0 none, 1 bias[col], 2 bias[row]
template<int BM, int BN, int BIAS, bool RELU, bool OUTBF16, bool FINAL>
__global__ __launch_bounds__(256) void gemm_bt_k(
    const u16* __restrict__ A, long long sA, int lda,
    const u16* __restrict__ Bt, long long sB, int ldb,
    void* __restrict__ C, long long sC, int ldc,
    int K, const float* __restrict__ bias,
    const float* __restrict__ gamma, const float* __restrict__ xres, long long sX) {
  constexpr int TM = BM / 32, TN = BN / 32;
  __shared__ u16 As[BM * 32];
  __shared__ u16 Bs[BN * 32];
  const int b = blockIdx.z;
  const u16* Ab = A + (size_t)sA * b;
  const u16* Bb = Bt + (size_t)sB * b;
  const int m0 = blockIdx.x * BM, n0 = blockIdx.y * BN;
  const int tid = threadIdx.x, lane = tid & 63, wave = tid >> 6;
  const int q = lane >> 4, cc = lane & 15;
  const int wm = (wave >> 1) * (BM / 2), wn = (wave & 1) * (BN / 2);

  floatx4 acc[TM][TN];
  #pragma unroll
  for (int mi = 0; mi < TM; mi++)
    #pragma unroll
    for (int ni = 0; ni < TN; ni++)
      acc[mi][ni] = floatx4{0.f, 0.f, 0.f, 0.f};

  for (int k0 = 0; k0 < K; k0 += 32) {
    #pragma unroll
    for (int i = 0; i < BM / 64; i++) {
      int slot = i * 256 + tid;
      lds_load16(Ab + (size_t)(m0 + (slot >> 2)) * lda + k0 + (slot & 3) * 8,
                 As + slot * 8);
    }
    #pragma unroll
    for (int i = 0; i < BN / 64; i++) {
      int slot = i * 256 + tid;
      lds_load16(Bb + (size_t)(n0 + (slot >> 2)) * ldb + k0 + (slot & 3) * 8,
                 Bs + slot * 8);
    }
    __syncthreads();
    bfx8 af[TM], bfr[TN];
    #pragma unroll
    for (int mi = 0; mi < TM; mi++)
      af[mi] = *(const bfx8*)(As + (wm + mi * 16 + cc) * 32 + q * 8);
    #pragma unroll
    for (int ni = 0; ni < TN; ni++)
      bfr[ni] = *(const bfx8*)(Bs + (wn + ni * 16 + cc) * 32 + q * 8);
    #pragma unroll
    for (int mi = 0; mi < TM; mi++)
      #pragma unroll
      for (int ni = 0; ni < TN; ni++)
        acc[mi][ni] = mfma16(af[mi], bfr[ni], acc[mi][ni]);
    __syncthreads();
  }

  float g0 = 0.f;
  if constexpr (FINAL) g0 = gamma[0];
  #pragma unroll
  for (int mi = 0; mi < TM; mi++) {
    #pragma unroll
    for (int ni = 0; ni < TN; ni++) {
      #pragma unroll
      for (int r = 0; r < 4; r++) {
        int row = m0 + wm + mi * 16 + q * 4 + r;   // C/D: row=(lane>>4)*4+reg
        int col = n0 + wn + ni * 16 + cc;          //      col=lane&15
        float v = acc[mi][ni][r];
        if constexpr (BIAS == 1) v += bias[col];
        if constexpr (BIAS == 2) v += bias[row];
        if constexpr (RELU) v = fmaxf(v, 0.f);
        if constexpr (FINAL)
          v = g0 * v + xres[(size_t)sX * b + (size_t)row * ldc + col];
        size_t idx = (size_t)sC * b + (size_t)row * ldc + col;
        if constexpr (OUTBF16) ((u16*)C)[idx] = f2bf(v);
        else ((float*)C)[idx] = v;
      }
    }
  }
}

// ---------------- fused attn + softmax (flash-style, 2-pass recompute) ------
// attnT[b][m][n] = sum_c gT[b][m][c] * fT[b][n][c]; softmax over n (contiguous)
// writes: outP[b][n][m] fp32 (d_out attn region), pT[b][m][n] bf16 (ws)
__global__ __launch_bounds__(256) void attn_softmax_k(
    const u16* __restrict__ gT, const u16* __restrict__ fT,
    float* __restrict__ outP, u16* __restrict__ pT) {
  __shared__ u16 Bs[64 * 128];      // fT n-chunk tile: 64 rows x 128 k
  __shared__ float Pt[64 * 65];     // p transpose staging (pad 65 vs bank conflicts)
  const int b = blockIdx.y;
  const int m0 = blockIdx.x * 64;
  const int tid = threadIdx.x, lane = tid & 63, wave = tid >> 6;
  const int q = lane >> 4, cc = lane & 15;
  const size_t bN = (size_t)b * NSP;

  // preload A-fragments (gT rows m0+wave*16+cc, full K=128) into registers
  bfx8 af[4];
  {
    const u16* gA = gT + (bN + m0 + wave * 16 + cc) * NCH;
    #pragma unroll
    for (int ks = 0; ks < 4; ks++) af[ks] = *(const bfx8*)(gA + ks * 32 + q * 8);
  }

  float rmax_[4], rsum_[4];
  #pragma unroll
  for (int r = 0; r < 4; r++) { rmax_[r] = -1e30f; rsum_[r] = 0.f; }

  // ---- pass 1: online (max, sum) over n ----
  for (int nc = 0; nc < NSP; nc += 64) {
    #pragma unroll
    for (int i = 0; i < 4; i++) {
      int slot = i * 256 + tid;
      lds_load16(fT + (bN + nc + (slot >> 4)) * NCH + (slot & 15) * 8,
                 Bs + slot * 8);
    }
    __syncthreads();
    floatx4 s[4];
    #pragma unroll
    for (int ni = 0; ni < 4; ni++) {
      s[ni] = floatx4{0.f, 0.f, 0.f, 0.f};
      #pragma unroll
      for (int ks = 0; ks < 4; ks++) {
        bfx8 bfr = *(const bfx8*)(Bs + (ni * 16 + cc) * 128 + ks * 32 + q * 8);
        s[ni] = mfma16(af[ks], bfr, s[ni]);
      }
    }
    #pragma unroll
    for (int r = 0; r < 4; r++) {
      float cm = fmaxf(fmaxf(s[0][r], s[1][r]), fmaxf(s[2][r], s[3][r]));
      cm = rmax16(cm);
      float nm = fmaxf(rmax_[r], cm);
      float cs = 0.f;
      #pragma unroll
      for (int ni = 0; ni < 4; ni++) cs += __expf(s[ni][r] - nm);
      cs = rsum16(cs);
      rsum_[r] = rsum_[r] * __expf(rmax_[r] - nm) + cs;
      rmax_[r] = nm;
    }
    __syncthreads();
  }
  float rinv_[4];
  #pragma unroll
  for (int r = 0; r < 4; r++) rinv_[r] = 1.f / rsum_[r];

  // ---- pass 2: recompute scores, emit p ----
  for (int nc = 0; nc < NSP; nc += 64) {
    #pragma unroll
    for (int i = 0; i < 4; i++) {
      int slot = i * 256 + tid;
      lds_load16(fT + (bN + nc + (slot >> 4)) * NCH + (slot & 15) * 8,
                 Bs + slot * 8);
    }
    __syncthreads();
    floatx4 s[4];
    #pragma unroll
    for (int ni = 0; ni < 4; ni++) {
      s[ni] = floatx4{0.f, 0.f, 0.f, 0.f};
      #pragma unroll
      for (int ks = 0; ks < 4; ks++) {
        bfx8 bfr = *(const bfx8*)(Bs + (ni * 16 + cc) * 128 + ks * 32 + q * 8);
        s[ni] = mfma16(af[ks], bfr, s[ni]);
      }
    }
    #pragma unroll
    for (int ni = 0; ni < 4; ni++) {
      #pragma unroll
      for (int r = 0; r < 4; r++) {
        float p = __expf(s[ni][r] - rmax_[r]) * rinv_[r];
        int ml = wave * 16 + q * 4 + r;   // m_local 0..63
        int nl = ni * 16 + cc;            // n_local 0..63
        pT[(bN + m0 + ml) * (size_t)NSP + nc + nl] = f2bf(p);
        Pt[nl * 65 + ml] = p;
      }
    }
    __syncthreads();
    // coalesced transposed write of p into d_out attn region: [b][n][m]
    #pragma unroll
    for (int s2 = 0; s2 < 4; s2++) {
      int nl = s2 * 16 + (tid >> 4);
      int ml = (tid & 15) * 4;
      floatx4 v;
      v[0] = Pt[nl * 65 + ml + 0];
      v[1] = Pt[nl * 65 + ml + 1];
      v[2] = Pt[nl * 65 + ml + 2];
      v[3] = Pt[nl * 65 + ml + 3];
      *(floatx4*)(outP + (bN + nc + nl) * (size_t)NSP + m0 + ml) = v;
    }
    __syncthreads();
  }
}

// ---------------- launcher ----------------
extern "C" void kernel_launch(void* const* d_in, const int* in_sizes, int n_in,
                              void* d_out, int out_size, void* d_ws, size_t ws_size,
                              hipStream_t stream) {
  const float* x     = (const float*)d_in[0];
  const float* wf1   = (const float*)d_in[1];
  const float* bf1   = (const float*)d_in[2];
  const float* wf2   = (const float*)d_in[3];
  const float* bf2   = (const float*)d_in[4];
  const float* wg1   = (const float*)d_in[5];
  const float* bg1   = (const float*)d_in[6];
  const float* wg2   = (const float*)d_in[7];
  const float* bg2   = (const float*)d_in[8];
  const float* wh    = (const float*)d_in[9];
  const float* bh    = (const float*)d_in[10];
  const float* gamma = (const float*)d_in[11];
  float* out = (float*)d_out;

  char* ws = (char*)d_ws;
  size_t off = 0;
  auto alloc = [&](size_t bytes) -> char* {
    char* p = ws + off;
    off += (bytes + 255) & ~(size_t)255;
    return p;
  };
  u16* wf1b = (u16*)alloc((size_t)NCH * NC * 2);
  u16* wf2b = (u16*)alloc((size_t)NCH * NCH * 2);
  u16* wg1b = (u16*)alloc((size_t)NCH * NC * 2);
  u16* wg2b = (u16*)alloc((size_t)NCH * NCH * 2);
  u16* whb  = (u16*)alloc((size_t)NC * NC * 2);
  u16* xT   = (u16*)alloc((size_t)NB * NSP * NC * 2);    // (B,N,C)
  u16* f1T  = (u16*)alloc((size_t)NB * NSP * NCH * 2);   // (B*N,Ch)
  u16* g1T  = (u16*)alloc((size_t)NB * NSP * NCH * 2);
  u16* fTb  = (u16*)alloc((size_t)NB * NSP * NCH * 2);
  u16* gTb  = (u16*)alloc((size_t)NB * NSP * NCH * 2);
  u16* hb   = (u16*)alloc((size_t)NB * NC * NSP * 2);    // (B,C,N)
  u16* pTb  = (u16*)alloc((size_t)NB * NSP * NSP * 2);   // (B,m,n) bf16

  // weights -> bf16
  cvt_bf16<<<dim3(128), 256, 0, stream>>>(wf1, wf1b, NCH * NC);
  cvt_bf16<<<dim3(64),  256, 0, stream>>>(wf2, wf2b, NCH * NCH);
  cvt_bf16<<<dim3(128), 256, 0, stream>>>(wg1, wg1b, NCH * NC);
  cvt_bf16<<<dim3(64),  256, 0, stream>>>(wg2, wg2b, NCH * NCH);
  cvt_bf16<<<dim3(256), 256, 0, stream>>>(wh,  whb,  NC * NC);

  // x -> xT bf16
  transpose_x<<<dim3(NSP / 64, NC / 64, NB), 256, 0, stream>>>(x, xT);

  const long long sX = (long long)NSP * NC;      // xT per-batch stride
  const long long sH = (long long)NC * NSP;      // h / out per-batch stride
  const long long sP = (long long)NSP * NSP;     // pT per-batch stride

  // f1T = relu(xT @ wf1^T + bf1)   (M=B*N folded, weights shared)
  gemm_bt_k<64, 128, 1, true, true, false><<<dim3(256, 1, 1), 256, 0, stream>>>(
      xT, 0, NC, wf1b, 0, NC, f1T, 0, NCH, NC, bf1, nullptr, nullptr, 0);
  gemm_bt_k<64, 128, 1, true, true, false><<<dim3(256, 1, 1), 256, 0, stream>>>(
      xT, 0, NC, wg1b, 0, NC, g1T, 0, NCH, NC, bg1, nullptr, nullptr, 0);
  // fT = f1T @ wf2^T + bf2
  gemm_bt_k<64, 128, 1, false, true, false><<<dim3(256, 1, 1), 256, 0, stream>>>(
      f1T, 0, NCH, wf2b, 0, NCH, fTb, 0, NCH, NCH, bf2, nullptr, nullptr, 0);
  gemm_bt_k<64, 128, 1, false, true, false><<<dim3(256, 1, 1), 256, 0, stream>>>(
      g1T, 0, NCH, wg2b, 0, NCH, gTb, 0, NCH, NCH, bg2, nullptr, nullptr, 0);
  // h[b] = wh @ x[b] + bh   (A=wh shared, Bt=xT[b], bias per row)
  gemm_bt_k<64, 128, 2, false, true, false><<<dim3(4, 32, NB), 256, 0, stream>>>(
      whb, 0, NC, xT, sX, NC, hb, sH, NSP, NC, bh, nullptr, nullptr, 0);

  // fused attn + softmax: writes d_out attn region + pT
  attn_softmax_k<<<dim3(NSP / 64, NB), 256, 0, stream>>>(
      gTb, fTb, out + OUT_OFF, pTb);

  // out[b] = gamma * (h[b] @ p[b]) + x[b]
  gemm_bt_k<256, 64, 0, false, false, true><<<dim3(1, 64, NB), 256, 0, stream>>>(
      hb, sH, NSP, pTb, sP, NSP, out, sH, NSP, NSP, nullptr, gamma, x, sH);

  (void)in_sizes; (void)n_in; (void)out_size; (void)ws_size;
}

// Round 2
// 563.193 us; speedup vs baseline: 1.3044x; 1.3044x over previous
//
#include <hip/hip_runtime.h>

typedef unsigned short u16;
typedef unsigned int   u32;
typedef float  floatx4 __attribute__((ext_vector_type(4)));
typedef __bf16 bfx8    __attribute__((ext_vector_type(8)));
typedef u16    u16x8   __attribute__((ext_vector_type(8)));

#define DEV __device__ __forceinline__

// Problem constants: B=4, C=256, Ch=128, N=H*W=4096
#define NB 4
#define NC 256
#define NCH 128
#define NSP 4096
#define OUT_OFF 4194304   // floats: 4*256*4096 out region precedes attn region

DEV u16 f2bf(float f) {
  u32 u = __builtin_bit_cast(u32, f);
  u = (u + 0x7fffu + ((u >> 16) & 1u)) >> 16;   // round-to-nearest-even
  return (u16)u;
}

DEV void lds_load16(const u16* g, u16* l) {
  __builtin_amdgcn_global_load_lds(
      (const __attribute__((address_space(1))) u32*)g,
      (__attribute__((address_space(3))) u32*)l, 16, 0, 0);
}

DEV floatx4 mfma16(bfx8 a, bfx8 b, floatx4 c) {
  return __builtin_amdgcn_mfma_f32_16x16x32_bf16(a, b, c, 0, 0, 0);
}

DEV float rsum16(float v) {
  #pragma unroll
  for (int m = 1; m < 16; m <<= 1) v += __shfl_xor(v, m, 64);
  return v;
}

// ---------------- fused weight converter (5 weights -> bf16) ----------------
__global__ __launch_bounds__(256) void cvt_all(
    const float* __restrict__ a0, const float* __restrict__ a1,
    const float* __restrict__ a2, const float* __restrict__ a3,
    const float* __restrict__ a4,
    u16* __restrict__ o0, u16* __restrict__ o1, u16* __restrict__ o2,
    u16* __restrict__ o3, u16* __restrict__ o4) {
  int i = blockIdx.x * 256 + threadIdx.x;
  if (i < 32768) { o0[i] = f2bf(a0[i]); return; }
  i -= 32768;
  if (i < 16384) { o1[i] = f2bf(a1[i]); return; }
  i -= 16384;
  if (i < 32768) { o2[i] = f2bf(a2[i]); return; }
  i -= 32768;
  if (i < 16384) { o3[i] = f2bf(a3[i]); return; }
  i -= 16384;
  o4[i] = f2bf(a4[i]);
}

__global__ __launch_bounds__(256) void zero_f(float* __restrict__ p, int n) {
  int i = blockIdx.x * 256 + threadIdx.x;
  if (i < n) p[i] = 0.f;
}

// x (B,C,N) fp32 -> xT (B,N,C) bf16
__global__ __launch_bounds__(256) void transpose_x(const float* __restrict__ x,
                                                   u16* __restrict__ xT) {
  __shared__ float T[64 * 65];
  const int b = blockIdx.z, c0 = blockIdx.y * 64, n0 = blockIdx.x * 64;
  const int tid = threadIdx.x;
  const int j = tid & 63, r0 = tid >> 6;
  const size_t xbase = ((size_t)b * NC + c0) * NSP + n0;
  #pragma unroll
  for (int s = 0; s < 16; s++) {
    int cl = s * 4 + r0;
    T[cl * 65 + j] = x[xbase + (size_t)cl * NSP + j];
  }
  __syncthreads();
  const size_t tbase = ((size_t)b * NSP + n0) * NC + c0;
  #pragma unroll
  for (int s = 0; s < 16; s++) {
    int nr = s * 4 + r0;
    xT[tbase + (size_t)nr * NC + j] = f2bf(T[j * 65 + nr]);
  }
}

// ---------------- generic B-transposed MFMA GEMM (frag-major LDS) -----------
// C[b][m][n] = sum_k A[b][m][k]*Bt[b][n][k] (+bias)(relu)(final: gamma*v + x)
// BIAS: 0 none, 1 bias[col], 2 bias[row]
template<int BM, int BN, int BK, int BIAS, bool RELU, bool OUTBF16, bool FINAL>
__global__ __launch_bounds__(256) void gemm_bt_k(
    const u16* __restrict__ A, long long sA, int lda,
    const u16* __restrict__ Bt, long long sB, int ldb,
    void* __restrict__ C, long long sC, int ldc,
    int K, const float* __restrict__ bias,
    const float* __restrict__ gamma, const float* __restrict__ xres) {
  constexpr int TM = BM / 32, TN = BN / 32, KS = BK / 32;
  __shared__ u16 As[BM * BK];
  __shared__ u16 Bs[BN * BK];
  const int b = blockIdx.z;
  const u16* Ab = A + (size_t)sA * b;
  const u16* Bb = Bt + (size_t)sB * b;
  const int m0 = blockIdx.x * BM, n0 = blockIdx.y * BN;
  const int tid = threadIdx.x, lane = tid & 63, wave = tid >> 6;
  const int q = lane >> 4, cc = lane & 15;
  const int wm = (wave >> 1) * (BM / 2), wn = (wave & 1) * (BN / 2);

  floatx4 acc[TM][TN];
  #pragma unroll
  for (int mi = 0; mi < TM; mi++)
    #pragma unroll
    for (int ni = 0; ni < TN; ni++)
      acc[mi][ni] = floatx4{0.f, 0.f, 0.f, 0.f};

  for (int k0 = 0; k0 < K; k0 += BK) {
    // frag-major staging: LDS chunk index = (frag_row*KS + ks)*64 + lane
    #pragma unroll
    for (int i = 0; i < BM * BK / 2048; i++) {
      int slot = i * 256 + tid;
      int fr = slot / (64 * KS);
      int ks = (slot / 64) % KS;
      int qq = (slot >> 4) & 3, cq = slot & 15;
      lds_load16(Ab + (size_t)(m0 + fr * 16 + cq) * lda + k0 + ks * 32 + qq * 8,
                 As + slot * 8);
    }
    #pragma unroll
    for (int i = 0; i < BN * BK / 2048; i++) {
      int slot = i * 256 + tid;
      int fr = slot / (64 * KS);
      int ks = (slot / 64) % KS;
      int qq = (slot >> 4) & 3, cq = slot & 15;
      lds_load16(Bb + (size_t)(n0 + fr * 16 + cq) * ldb + k0 + ks * 32 + qq * 8,
                 Bs + slot * 8);
    }
    __syncthreads();
    #pragma unroll
    for (int ks = 0; ks < KS; ks++) {
      bfx8 af[TM], bfr[TN];
      #pragma unroll
      for (int mi = 0; mi < TM; mi++)
        af[mi] = *(const bfx8*)(As + ((((wm >> 4) + mi) * KS + ks) * 64 + lane) * 8);
      #pragma unroll
      for (int ni = 0; ni < TN; ni++)
        bfr[ni] = *(const bfx8*)(Bs + ((((wn >> 4) + ni) * KS + ks) * 64 + lane) * 8);
      #pragma unroll
      for (int mi = 0; mi < TM; mi++)
        #pragma unroll
        for (int ni = 0; ni < TN; ni++)
          acc[mi][ni] = mfma16(af[mi], bfr[ni], acc[mi][ni]);
    }
    __syncthreads();
  }

  float g0 = 0.f;
  if constexpr (FINAL) g0 = gamma[0];
  #pragma unroll
  for (int mi = 0; mi < TM; mi++) {
    #pragma unroll
    for (int ni = 0; ni < TN; ni++) {
      #pragma unroll
      for (int r = 0; r < 4; r++) {
        int row = m0 + wm + mi * 16 + q * 4 + r;   // C/D: row=(lane>>4)*4+reg
        int col = n0 + wn + ni * 16 + cc;          //      col=lane&15
        float v = acc[mi][ni][r];
        if constexpr (BIAS == 1) v += bias[col];
        if constexpr (BIAS == 2) v += bias[row];
        if constexpr (RELU) v = fmaxf(v, 0.f);
        if constexpr (FINAL)
          v = g0 * v + xres[(size_t)sC * b + (size_t)row * ldc + col];
        size_t idx = (size_t)sC * b + (size_t)row * ldc + col;
        if constexpr (OUTBF16) ((u16*)C)[idx] = f2bf(v);
        else ((float*)C)[idx] = v;
      }
    }
  }
}

// ---------------- attn row-sum: rsum[b][m] = sum_n exp(s[m][n]) -------------
__global__ __launch_bounds__(256) void attn_rowsum_k(
    const u16* __restrict__ gT, const u16* __restrict__ fT,
    float* __restrict__ rsum) {
  __shared__ u16 Bs[64 * 128];
  const int b = blockIdx.z, m0 = blockIdx.y * 64, n0 = blockIdx.x * 512;
  const int tid = threadIdx.x, lane = tid & 63, wave = tid >> 6;
  const int q = lane >> 4, cc = lane & 15;
  const size_t bN = (size_t)b * NSP;

  bfx8 af[4];
  {
    const u16* gA = gT + (bN + m0 + wave * 16 + cc) * NCH;
    #pragma unroll
    for (int ks = 0; ks < 4; ks++) af[ks] = *(const bfx8*)(gA + ks * 32 + q * 8);
  }
  float ps[4] = {0.f, 0.f, 0.f, 0.f};

  for (int sc = 0; sc < 8; sc++) {
    const int nc = n0 + sc * 64;
    #pragma unroll
    for (int i = 0; i < 4; i++) {
      int slot = i * 256 + tid;
      int ni = slot >> 8, ks = (slot >> 6) & 3;
      int qq = (slot >> 4) & 3, cq = slot & 15;
      lds_load16(fT + (bN + nc + ni * 16 + cq) * NCH + ks * 32 + qq * 8,
                 Bs + slot * 8);
    }
    __syncthreads();
    #pragma unroll
    for (int ni = 0; ni < 4; ni++) {
      floatx4 s = floatx4{0.f, 0.f, 0.f, 0.f};
      #pragma unroll
      for (int ks = 0; ks < 4; ks++) {
        bfx8 bfr = *(const bfx8*)(Bs + ((ni * 4 + ks) * 64 + lane) * 8);
        s = mfma16(af[ks], bfr, s);
      }
      #pragma unroll
      for (int r = 0; r < 4; r++) ps[r] += __expf(fminf(s[r], 80.f));
    }
    __syncthreads();
  }
  #pragma unroll
  for (int r = 0; r < 4; r++) ps[r] = rsum16(ps[r]);
  if (cc == 0) {
    #pragma unroll
    for (int r = 0; r < 4; r++)
      atomicAdd(&rsum[bN + m0 + wave * 16 + q * 4 + r], ps[r]);
  }
}

// ---------------- attn p-emit: recompute s, p = exp(s)/rsum -----------------
// writes outP[b][n][m] fp32 (d_out attn region) + pT[b][m][n] bf16 (ws)
__global__ __launch_bounds__(256) void attn_p_k(
    const u16* __restrict__ gT, const u16* __restrict__ fT,
    const float* __restrict__ rsum,
    float* __restrict__ outP, u16* __restrict__ pT) {
  __shared__ u16 Bs[64 * 128];
  __shared__ float Pt[64 * 68];
  __shared__ u16 Pb[64 * 72];
  const int b = blockIdx.z, m0 = blockIdx.y * 64, n0 = blockIdx.x * 256;
  const int tid = threadIdx.x, lane = tid & 63, wave = tid >> 6;
  const int q = lane >> 4, cc = lane & 15;
  const size_t bN = (size_t)b * NSP;

  bfx8 af[4];
  {
    const u16* gA = gT + (bN + m0 + wave * 16 + cc) * NCH;
    #pragma unroll
    for (int ks = 0; ks < 4; ks++) af[ks] = *(const bfx8*)(gA + ks * 32 + q * 8);
  }
  float rinvv[4];
  #pragma unroll
  for (int r = 0; r < 4; r++)
    rinvv[r] = 1.f / rsum[bN + m0 + wave * 16 + q * 4 + r];

  for (int sc = 0; sc < 4; sc++) {
    const int nc = n0 + sc * 64;
    #pragma unroll
    for (int i = 0; i < 4; i++) {
      int slot = i * 256 + tid;
      int ni = slot >> 8, ks = (slot >> 6) & 3;
      int qq = (slot >> 4) & 3, cq = slot & 15;
      lds_load16(fT + (bN + nc + ni * 16 + cq) * NCH + ks * 32 + qq * 8,
                 Bs + slot * 8);
    }
    __syncthreads();
    #pragma unroll
    for (int ni = 0; ni < 4; ni++) {
      floatx4 s = floatx4{0.f, 0.f, 0.f, 0.f};
      #pragma unroll
      for (int ks = 0; ks < 4; ks++) {
        bfx8 bfr = *(const bfx8*)(Bs + ((ni * 4 + ks) * 64 + lane) * 8);
        s = mfma16(af[ks], bfr, s);
      }
      #pragma unroll
      for (int r = 0; r < 4; r++) {
        float p = __expf(fminf(s[r], 80.f)) * rinvv[r];
        int ml = wave * 16 + q * 4 + r;
        int nl = ni * 16 + cc;
        Pt[nl * 68 + ml] = p;
        Pb[ml * 72 + nl] = f2bf(p);
      }
    }
    __syncthreads();
    // outP rows n: 64 rows x 64 floats, coalesced float4
    #pragma unroll
    for (int i = 0; i < 4; i++) {
      int slot = i * 256 + tid;
      int nl = slot >> 4, f4 = slot & 15;
      floatx4 v = *(const floatx4*)(Pt + nl * 68 + f4 * 4);
      *(floatx4*)(outP + (bN + nc + nl) * NSP + m0 + f4 * 4) = v;
    }
    // pT rows m: 64 rows x 64 bf16, coalesced u16x8
    #pragma unroll
    for (int i = 0; i < 2; i++) {
      int slot = i * 256 + tid;
      int ml = slot >> 3, c8 = slot & 7;
      u16x8 v = *(const u16x8*)(Pb + ml * 72 + c8 * 8);
      *(u16x8*)(pT + (bN + m0 + ml) * NSP + nc + c8 * 8) = v;
    }
    __syncthreads();
  }
}

// ---------------- launcher ----------------
extern "C" void kernel_launch(void* const* d_in, const int* in_sizes, int n_in,
                              void* d_out, int out_size, void* d_ws, size_t ws_size,
                              hipStream_t stream) {
  const float* x     = (const float*)d_in[0];
  const float* wf1   = (const float*)d_in[1];
  const float* bf1   = (const float*)d_in[2];
  const float* wf2   = (const float*)d_in[3];
  const float* bf2   = (const float*)d_in[4];
  const float* wg1   = (const float*)d_in[5];
  const float* bg1   = (const float*)d_in[6];
  const float* wg2   = (const float*)d_in[7];
  const float* bg2   = (const float*)d_in[8];
  const float* wh    = (const float*)d_in[9];
  const float* bh    = (const float*)d_in[10];
  const float* gamma = (const float*)d_in[11];
  float* out = (float*)d_out;

  char* ws = (char*)d_ws;
  size_t off = 0;
  auto alloc = [&](size_t bytes) -> char* {
    char* p = ws + off;
    off += (bytes + 255) & ~(size_t)255;
    return p;
  };
  u16* wf1b = (u16*)alloc((size_t)NCH * NC * 2);
  u16* wf2b = (u16*)alloc((size_t)NCH * NCH * 2);
  u16* wg1b = (u16*)alloc((size_t)NCH * NC * 2);
  u16* wg2b = (u16*)alloc((size_t)NCH * NCH * 2);
  u16* whb  = (u16*)alloc((size_t)NC * NC * 2);
  u16* xT   = (u16*)alloc((size_t)NB * NSP * NC * 2);    // (B,N,C)
  u16* f1T  = (u16*)alloc((size_t)NB * NSP * NCH * 2);
  u16* g1T  = (u16*)alloc((size_t)NB * NSP * NCH * 2);
  u16* fTb  = (u16*)alloc((size_t)NB * NSP * NCH * 2);
  u16* gTb  = (u16*)alloc((size_t)NB * NSP * NCH * 2);
  u16* hb   = (u16*)alloc((size_t)NB * NC * NSP * 2);    // (B,C,N)
  float* rs = (float*)alloc((size_t)NB * NSP * 4);       // row sums
  u16* pTb  = (u16*)alloc((size_t)NB * NSP * NSP * 2);   // (B,m,n) bf16

  cvt_all<<<dim3(640), 256, 0, stream>>>(wf1, wf2, wg1, wg2, wh,
                                         wf1b, wf2b, wg1b, wg2b, whb);
  transpose_x<<<dim3(NSP / 64, NC / 64, NB), 256, 0, stream>>>(x, xT);
  zero_f<<<dim3(NB * NSP / 256), 256, 0, stream>>>(rs, NB * NSP);

  const long long sX = (long long)NSP * NC;
  const long long sH = (long long)NC * NSP;
  const long long sP = (long long)NSP * NSP;

  // f1T = relu(xT @ wf1^T + bf1); same for g
  gemm_bt_k<64, 128, 32, 1, true, true, false><<<dim3(256, 1, 1), 256, 0, stream>>>(
      xT, 0, NC, wf1b, 0, NC, f1T, 0, NCH, NC, bf1, nullptr, nullptr);
  gemm_bt_k<64, 128, 32, 1, true, true, false><<<dim3(256, 1, 1), 256, 0, stream>>>(
      xT, 0, NC, wg1b, 0, NC, g1T, 0, NCH, NC, bg1, nullptr, nullptr);
  gemm_bt_k<64, 128, 32, 1, false, true, false><<<dim3(256, 1, 1), 256, 0, stream>>>(
      f1T, 0, NCH, wf2b, 0, NCH, fTb, 0, NCH, NCH, bf2, nullptr, nullptr);
  gemm_bt_k<64, 128, 32, 1, false, true, false><<<dim3(256, 1, 1), 256, 0, stream>>>(
      g1T, 0, NCH, wg2b, 0, NCH, gTb, 0, NCH, NCH, bg2, nullptr, nullptr);
  // h[b] = wh @ x[b] + bh
  gemm_bt_k<64, 128, 32, 2, false, true, false><<<dim3(4, 32, NB), 256, 0, stream>>>(
      whb, 0, NC, xT, sX, NC, hb, sH, NSP, NC, bh, nullptr, nullptr);

  // attn: row sums (atomic) then p emission
  attn_rowsum_k<<<dim3(8, 64, NB), 256, 0, stream>>>(gTb, fTb, rs);
  attn_p_k<<<dim3(16, 64, NB), 256, 0, stream>>>(gTb, fTb, rs, out + OUT_OFF, pTb);

  // out[b] = gamma * (h[b] @ p[b]) + x[b]
  gemm_bt_k<128, 128, 64, 0, false, false, true><<<dim3(2, 32, NB), 256, 0, stream>>>(
      hb, sH, NSP, pTb, sP, NSP, out, sH, NSP, NSP, nullptr, gamma, x);

  (void)in_sizes; (void)n_in; (void)out_size; (void)ws_size;
}